// Round 9
// baseline (213.741 us; speedup 1.0000x reference)
//
#include <hip/hip_runtime.h>

#define B 8
#define E 2000
#define NTRI 10000
#define NRELS 25
#define KT 16
#define TT 3
#define LL 32
#define TAU1 10.0f
#define XBLK 8192
#define XTHR 256

typedef __attribute__((ext_vector_type(4))) float f32x4;

__device__ __forceinline__ float clip01(float x) { return fminf(fmaxf(x, 0.0f), 1.0f); }

__device__ __forceinline__ void proc_e2t(f32x4 v, int i, int* __restrict__ heads) {
    if (v.x != 0.f || v.y != 0.f || v.z != 0.f || v.w != 0.f) {
        int f = i * 4;
        float c[4] = {v.x, v.y, v.z, v.w};
#pragma unroll
        for (int k = 0; k < 4; k++)
            if (c[k] != 0.f) {
                int a = f + k;
                int head = a / NTRI;
                heads[a - head * NTRI] = head;
            }
    }
}

__device__ __forceinline__ void proc_t2e(f32x4 v, int i, int* __restrict__ tails) {
    if (v.x != 0.f || v.y != 0.f || v.z != 0.f || v.w != 0.f) {
        int f = i * 4;
        float c[4] = {v.x, v.y, v.z, v.w};
#pragma unroll
        for (int k = 0; k < 4; k++)
            if (c[k] != 0.f) {
                int a = f + k;
                int j = a / E;
                tails[j] = a - j * E;
            }
    }
}

// One pass over all dense one-hot inputs. One-hot structure => each output
// slot has exactly one writer: plain stores, no atomics, no memset node.
// Big sweeps: NON-TEMPORAL loads (R8: -10 us) + x2 within-array unroll
// (2 independent NT loads in flight per thread; testing whether MLP is the
// new limiter now that NT removed the cache-allocation throttle).
__global__ void __launch_bounds__(XTHR) extract_all(
        const f32x4* __restrict__ e2t, const f32x4* __restrict__ t2e,
        const f32x4* __restrict__ t2r, const float4* __restrict__ ix,
        const float4* __restrict__ tm,
        int* __restrict__ heads, int* __restrict__ tails, int* __restrict__ rels,
        int* __restrict__ ent, int* __restrict__ tidx, float4* __restrict__ out4) {
    const int gtid = blockIdx.x * XTHR + threadIdx.x;
    const int gs = XBLK * XTHR;

    // input_x [B,E]: ent[b] = col  (4000 float4)
    for (int i = gtid; i < B * E / 4; i += gs) {
        float4 v = ix[i];
        if (v.x != 0.f || v.y != 0.f || v.z != 0.f || v.w != 0.f) {
            int f = i * 4;
            float c[4] = {v.x, v.y, v.z, v.w};
#pragma unroll
            for (int k = 0; k < 4; k++)
                if (c[k] != 0.f) { int a = f + k; int b = a / E; ent[b] = a - b * E; }
        }
    }
    // type_mat [E,KT]: tidx[e] = col  (8000 float4)
    for (int i = gtid; i < E * KT / 4; i += gs) {
        float4 v = tm[i];
        if (v.x != 0.f || v.y != 0.f || v.z != 0.f || v.w != 0.f) {
            int f = i * 4;
            float c[4] = {v.x, v.y, v.z, v.w};
#pragma unroll
            for (int k = 0; k < 4; k++)
                if (c[k] != 0.f) { int a = f + k; int e = a / KT; tidx[e] = a - e * KT; }
        }
    }
    // zero d_out (4000 float4) so mega_prop can atomicAdd into it
    float4 z = make_float4(0.f, 0.f, 0.f, 0.f);
    for (int i = gtid; i < B * E / 4; i += gs) out4[i] = z;

    // triple2r [NTRI,NRELS] (62500 float4): rels[j]  — NT
    for (int i = gtid; i < NTRI * NRELS / 4; i += gs) {
        f32x4 v = __builtin_nontemporal_load(&t2r[i]);
        if (v.x != 0.f || v.y != 0.f || v.z != 0.f || v.w != 0.f) {
            int f = i * 4;
            float c[4] = {v.x, v.y, v.z, v.w};
#pragma unroll
            for (int k = 0; k < 4; k++)
                if (c[k] != 0.f) {
                    int a = f + k;
                    int j = a / NRELS;
                    rels[j] = a - j * NRELS;
                }
        }
    }
    // e2triple [E,NTRI] (5M float4): heads[j] — NT, x2 within-array
    {
        const int half = E * NTRI / 8;  // 2,500,000
        for (int i = gtid; i < half; i += gs) {
            f32x4 v0 = __builtin_nontemporal_load(&e2t[i]);
            f32x4 v1 = __builtin_nontemporal_load(&e2t[i + half]);
            proc_e2t(v0, i, heads);
            proc_e2t(v1, i + half, heads);
        }
    }
    // triple2e [NTRI,E] (5M float4): tails[j] — NT, x2 within-array
    {
        const int half = NTRI * E / 8;
        for (int i = gtid; i < half; i += gs) {
            f32x4 v0 = __builtin_nontemporal_load(&t2e[i]);
            f32x4 v1 = __builtin_nontemporal_load(&t2e[i + half]);
            proc_t2e(v0, i, tails);
            proc_t2e(v1, i + half, tails);
        }
    }
}

// One block per (b,l); all TT rounds internally, s stays in LDS.
// mask (tail-rel existence bitmask) is built per-block in LDS during the t=0
// scan. t=2 fuses the l-reduction via global fp32 atomics into out.
__global__ void __launch_bounds__(512) mega_prop(
        const int* __restrict__ heads, const int* __restrict__ tails,
        const int* __restrict__ rels, const int* __restrict__ ent,
        const int* __restrict__ tidx,
        const float* __restrict__ w, const float* __restrict__ h,
        const float* __restrict__ h_type, const float* __restrict__ alpha,
        const float* __restrict__ beta, const float* __restrict__ h_x,
        const float* __restrict__ h_x_type, const float* __restrict__ alpha_x,
        const float* __restrict__ beta_x, const float* __restrict__ weight,
        float* __restrict__ out) {
    __shared__ float prev[E];
    __shared__ float acc[E];
    __shared__ unsigned int mask_s[E];
    __shared__ int tidx_s[E];
    __shared__ float wrow[NRELS];
    __shared__ float hp[NRELS - 1];
    __shared__ float htpL[KT];
    __shared__ unsigned int relflag;
    __shared__ float extra_s;

    const int NT = 512;
    const int blk = blockIdx.x, b = blk >> 5, l = blk & 31, tid = threadIdx.x;
    const int ent_b = ent[b];

    for (int e = tid; e < E; e += NT) {
        acc[e] = 0.f;
        mask_s[e] = 0u;
        tidx_s[e] = tidx[e];
    }
    if (tid == 0) { relflag = 0u; extra_s = 1.f; }

    const uint4* h4 = (const uint4*)heads;
    const uint4* t4 = (const uint4*)tails;
    const uint4* r4 = (const uint4*)rels;

    for (int t = 0; t < TT; t++) {
        const int tl = t * LL + l;
        if (tid == 0) {
            const float* wr = w + tl * NRELS;
            float mx = wr[0];
            for (int r = 1; r < NRELS; r++) mx = fmaxf(mx, wr[r]);
            float ex[NRELS], s = 0.f;
            for (int r = 0; r < NRELS; r++) { ex[r] = expf(wr[r] - mx); s += ex[r]; }
            float inv = 1.f / s;
            for (int r = 0; r < NRELS; r++) wrow[r] = ex[r] * inv;
        }
        if (tid >= 64 && tid < 64 + NRELS - 1)
            hp[tid - 64] = clip01(h[tl * (NRELS - 1) + (tid - 64)] / TAU1);
        if (tid >= 128 && tid < 128 + KT)
            htpL[tid - 128] = clip01(h_type[tl * KT + (tid - 128)] / TAU1);
        __syncthreads();

        if (t == 0) {
            for (int i = tid; i < NTRI / 4; i += NT) {
                uint4 hh = h4[i], ttv = t4[i], rr = r4[i];
#pragma unroll
                for (int k = 0; k < 4; k++) {
                    unsigned int hd = (k == 0) ? hh.x : (k == 1) ? hh.y : (k == 2) ? hh.z : hh.w;
                    unsigned int ta = (k == 0) ? ttv.x : (k == 1) ? ttv.y : (k == 2) ? ttv.z : ttv.w;
                    unsigned int r  = (k == 0) ? rr.x : (k == 1) ? rr.y : (k == 2) ? rr.z : rr.w;
                    if (r < NRELS - 1) atomicOr(&mask_s[ta], 1u << r);  // hidden_base flags
                    if ((int)hd == ent_b) {
                        atomicAdd(&acc[ta], wrow[r]);
                        atomicOr(&relflag, 1u << r);
                    }
                }
            }
        } else {
            for (int i = tid; i < NTRI / 4; i += NT) {
                uint4 hh = h4[i], ttv = t4[i], rr = r4[i];
#pragma unroll
                for (int k = 0; k < 4; k++) {
                    unsigned int hd = (k == 0) ? hh.x : (k == 1) ? hh.y : (k == 2) ? hh.z : hh.w;
                    float pv = prev[hd];
                    if (pv != 0.f) {
                        unsigned int ta = (k == 0) ? ttv.x : (k == 1) ? ttv.y : (k == 2) ? ttv.z : ttv.w;
                        unsigned int r  = (k == 0) ? rr.x : (k == 1) ? rr.y : (k == 2) ? rr.z : rr.w;
                        atomicAdd(&acc[ta], pv * wrow[r]);
                    }
                }
            }
        }
        __syncthreads();

        const float a = clip01(alpha[tl] / TAU1);
        const float bb = clip01(beta[tl] / TAU1);
        const float base = 1.f - clip01(a + bb);

        if (t == 0 && tid == 0) {
            unsigned int fl = relflag;
            float hxlin = 0.f;
            for (int i = 0; i < NRELS - 1; i++) {
                int pi = (i < 12) ? (12 + i) : (i - 12);  // concat(hx_raw[:,12:24], hx_raw[:,0:12])
                if ((fl >> pi) & 1u) hxlin += clip01(h_x[l * (NRELS - 1) + i] / TAU1);
            }
            float htx = clip01(h_x_type[l * KT + tidx_s[ent_b]] / TAU1);
            float ax = clip01(alpha_x[l] / TAU1), bx = clip01(beta_x[l] / TAU1);
            extra_s = clip01(a * htx + bb * hxlin) + (1.f - clip01(ax + bx));
        }
        __syncthreads();

        const float extra = (t == 0) ? extra_s : 1.f;

        if (t < TT - 1) {
            for (int e = tid; e < E; e += NT) {
                unsigned int m = mask_s[e];
                float dot = 0.f;
#pragma unroll
                for (int i = 0; i < NRELS - 1; i++) dot += ((m >> i) & 1u) ? hp[i] : 0.f;
                float he = clip01(a * htpL[tidx_s[e]] + bb * dot) + base;
                prev[e] = acc[e] * he * extra;
                acc[e] = 0.f;
            }
        } else {
            float tw = tanhf(weight[l]);
            for (int e = tid; e < E; e += NT) {
                unsigned int m = mask_s[e];
                float dot = 0.f;
#pragma unroll
                for (int i = 0; i < NRELS - 1; i++) dot += ((m >> i) & 1u) ? hp[i] : 0.f;
                float he = clip01(a * htpL[tidx_s[e]] + bb * dot) + base;
                atomicAdd(&out[b * E + e], acc[e] * he * tw);
            }
        }
        __syncthreads();
    }
}

extern "C" void kernel_launch(void* const* d_in, const int* in_sizes, int n_in,
                              void* d_out, int out_size, void* d_ws, size_t ws_size,
                              hipStream_t stream) {
    const float* input_x  = (const float*)d_in[0];
    const float* type_mat = (const float*)d_in[1];
    const float* e2triple = (const float*)d_in[2];
    const float* triple2e = (const float*)d_in[3];
    const float* triple2r = (const float*)d_in[4];
    const float* w        = (const float*)d_in[5];
    const float* weight   = (const float*)d_in[6];
    const float* h        = (const float*)d_in[7];
    const float* h_x      = (const float*)d_in[8];
    const float* h_type   = (const float*)d_in[9];
    const float* h_x_type = (const float*)d_in[10];
    const float* alpha    = (const float*)d_in[11];
    const float* beta     = (const float*)d_in[12];
    const float* alpha_x  = (const float*)d_in[13];
    const float* beta_x   = (const float*)d_in[14];
    (void)in_sizes; (void)n_in; (void)out_size; (void)ws_size;

    // All ws arrays are fully written by extract_all before mega_prop reads
    // them (one-hot structure => every slot has exactly one writer), so no
    // memset node is needed despite the 0xAA poison.
    char* ws = (char*)d_ws;
    int* heads = (int*)ws;                         // NTRI
    int* tails = heads + ((NTRI + 63) & ~63);      // NTRI
    int* rels  = tails + ((NTRI + 63) & ~63);      // NTRI
    int* ent   = rels + ((NTRI + 63) & ~63);       // B
    int* tidx  = ent + 64;                         // E

    extract_all<<<XBLK, XTHR, 0, stream>>>((const f32x4*)e2triple, (const f32x4*)triple2e,
                                           (const f32x4*)triple2r, (const float4*)input_x,
                                           (const float4*)type_mat,
                                           heads, tails, rels, ent, tidx, (float4*)d_out);

    mega_prop<<<B * LL, 512, 0, stream>>>(heads, tails, rels, ent, tidx, w, h, h_type,
                                          alpha, beta, h_x, h_x_type, alpha_x, beta_x,
                                          weight, (float*)d_out);
}